// Round 3
// baseline (3264.164 us; speedup 1.0000x reference)
//
#include <hip/hip_runtime.h>

// Residual VQ on MI355X (gfx950).
// z: [8, 32768, 32] f32; codebooks: [10, 512, 32] f32.
// Outputs (flat f32 in d_out): quantized [B,N,D], indices [B,N,Q] (as float),
// commit_loss [Q] (zeros).
//
// R3: 4 points per thread so each L1-broadcast codeword load feeds 4x the
// FMA work (R1 was L1-broadcast-bound at VALUBusy=33%). Candidate double-
// buffered in VGPRs (A/B float4[8] ping-pong). oacc removed from the hot
// kernel (VGPR budget); a replay kernel re-runs the bit-exact straight-
// through chain from the stored indices to produce `quantized`.
// Distance arithmetic is bit-identical to R1 (absmax 0.0): 8-accumulator
// j&7 dot, dist = fma(-2,dot,rr)+cc, strict-< first-min argmin.

#define RVQ_B 8
#define RVQ_N 32768
#define RVQ_D 32
#define RVQ_Q 10
#define RVQ_C 512

static constexpr int  NPTS     = RVQ_B * RVQ_N;             // 262144
static constexpr long IDX_OFF  = (long)NPTS * RVQ_D;        // 8388608
static constexpr long LOSS_OFF = IDX_OFF + (long)NPTS * RVQ_Q;

// ---------------------------------------------------------------------------
// Kernel 1: per-codeword squared norms -> ws[Q*C]
__global__ void rvq_cb_norms(const float* __restrict__ cb, float* __restrict__ ws) {
    int i = blockIdx.x * blockDim.x + threadIdx.x;
    if (i >= RVQ_Q * RVQ_C) return;
    const float* c = cb + (long)i * RVQ_D;
    float a[8];
#pragma unroll
    for (int j = 0; j < 8; ++j) a[j] = c[j] * c[j];
#pragma unroll
    for (int j = 8; j < RVQ_D; ++j) a[j & 7] = fmaf(c[j], c[j], a[j & 7]);
    ws[i] = ((a[0] + a[1]) + (a[2] + a[3])) + ((a[4] + a[5]) + (a[6] + a[7]));
}

// ---------------------------------------------------------------------------
// Kernel 2: argmin search, 4 points per thread. Writes only indices.
__global__ __launch_bounds__(256) void rvq_search(const float* __restrict__ z,
                                                  const float* __restrict__ cb,
                                                  const float* __restrict__ cbn,
                                                  float* __restrict__ out) {
    const int  t  = blockIdx.x * 256 + threadIdx.x;   // 65536 threads
    const long p0 = (long)t * 4;

    float r[4][RVQ_D];  // residuals for 4 points
    {
        const float4* zp = (const float4*)(z + p0 * RVQ_D);
#pragma unroll
        for (int i = 0; i < 4; ++i)
#pragma unroll
            for (int w = 0; w < 8; ++w) {
                const float4 v = zp[i * 8 + w];
                r[i][w * 4 + 0] = v.x; r[i][w * 4 + 1] = v.y;
                r[i][w * 4 + 2] = v.z; r[i][w * 4 + 3] = v.w;
            }
    }

#pragma unroll 1
    for (int q = 0; q < RVQ_Q; ++q) {
        // rr per point: 8-acc pairwise (bit-identical to R1)
        float rr[4];
#pragma unroll
        for (int i = 0; i < 4; ++i) {
            float a[8];
#pragma unroll
            for (int j = 0; j < 8; ++j) a[j] = r[i][j] * r[i][j];
#pragma unroll
            for (int j = 8; j < RVQ_D; ++j) a[j & 7] = fmaf(r[i][j], r[i][j], a[j & 7]);
            rr[i] = ((a[0] + a[1]) + (a[2] + a[3])) + ((a[4] + a[5]) + (a[6] + a[7]));
        }

        const float4* cq4 = (const float4*)(cb + (long)q * RVQ_C * RVQ_D);
        const float*  nq_ = cbn + q * RVQ_C;

        float best[4];
        int   bidx[4];
#pragma unroll
        for (int i = 0; i < 4; ++i) { best[i] = __builtin_inff(); bidx[i] = 0; }

        float4 A[8], B[8];
#pragma unroll
        for (int w = 0; w < 8; ++w) A[w] = cq4[w];  // candidate 0

        // evaluate candidate k (data in 'cw') against all 4 points
        auto EVAL = [&](const float4* cw, int k) {
            const float nq = nq_[k];
#pragma unroll
            for (int i = 0; i < 4; ++i) {
                float acc[8];
#pragma unroll
                for (int j = 0; j < 8; ++j) {
                    const float4 cv = cw[j >> 2];
                    const float  ce = (j & 3) == 0 ? cv.x : (j & 3) == 1 ? cv.y : (j & 3) == 2 ? cv.z : cv.w;
                    acc[j] = r[i][j] * ce;
                }
#pragma unroll
                for (int j = 8; j < RVQ_D; ++j) {
                    const float4 cv = cw[j >> 2];
                    const float  ce = (j & 3) == 0 ? cv.x : (j & 3) == 1 ? cv.y : (j & 3) == 2 ? cv.z : cv.w;
                    acc[j & 7] = fmaf(r[i][j], ce, acc[j & 7]);
                }
                const float dot = ((acc[0] + acc[1]) + (acc[2] + acc[3])) +
                                  ((acc[4] + acc[5]) + (acc[6] + acc[7]));
                const float dist = fmaf(-2.0f, dot, rr[i]) + nq;
                if (dist < best[i]) { best[i] = dist; bidx[i] = k; }  // first-min
            }
        };

#pragma unroll 1
        for (int k = 0; k < RVQ_C; k += 2) {
#pragma unroll
            for (int w = 0; w < 8; ++w) B[w] = cq4[(k + 1) * 8 + w];  // prefetch k+1
            EVAL(A, k);
            if (k + 2 < RVQ_C) {
#pragma unroll
                for (int w = 0; w < 8; ++w) A[w] = cq4[(k + 2) * 8 + w];  // prefetch k+2
            }
            EVAL(B, k + 1);
        }

        // per point: store index, gather chosen codeword, update residual
        // (bit-identical straight-through chain, oacc handled by replay kernel)
#pragma unroll
        for (int i = 0; i < 4; ++i) {
            out[IDX_OFF + (p0 + i) * RVQ_Q + q] = (float)bidx[i];
            const float4* cwb = cq4 + (long)bidx[i] * 8;
            float cw[RVQ_D];
#pragma unroll
            for (int w = 0; w < 8; ++w) {
                const float4 v = cwb[w];
                cw[w * 4 + 0] = v.x; cw[w * 4 + 1] = v.y;
                cw[w * 4 + 2] = v.z; cw[w * 4 + 3] = v.w;
            }
#pragma unroll
            for (int d = 0; d < RVQ_D; ++d) {
                const float qst = r[i][d] + (cw[d] - r[i][d]);
                r[i][d] = r[i][d] - qst;
            }
        }
    }
}

// ---------------------------------------------------------------------------
// Kernel 3: replay the straight-through chain from stored indices; writes
// quantized + commit_loss. Bit-identical op order to the reference.
__global__ __launch_bounds__(256) void rvq_replay(const float* __restrict__ z,
                                                  const float* __restrict__ cb,
                                                  float* __restrict__ out) {
    const int p = blockIdx.x * 256 + threadIdx.x;  // 262144 threads

    float r[RVQ_D], oacc[RVQ_D];
    {
        const float4* zp = (const float4*)(z + (long)p * RVQ_D);
#pragma unroll
        for (int w = 0; w < 8; ++w) {
            const float4 v = zp[w];
            r[w * 4 + 0] = v.x; r[w * 4 + 1] = v.y;
            r[w * 4 + 2] = v.z; r[w * 4 + 3] = v.w;
        }
    }
#pragma unroll
    for (int d = 0; d < RVQ_D; ++d) oacc[d] = 0.0f;

#pragma unroll 1
    for (int q = 0; q < RVQ_Q; ++q) {
        const int idx = (int)out[IDX_OFF + (long)p * RVQ_Q + q];
        const float4* cwb = (const float4*)(cb + ((long)q * RVQ_C + idx) * RVQ_D);
        float cw[RVQ_D];
#pragma unroll
        for (int w = 0; w < 8; ++w) {
            const float4 v = cwb[w];
            cw[w * 4 + 0] = v.x; cw[w * 4 + 1] = v.y;
            cw[w * 4 + 2] = v.z; cw[w * 4 + 3] = v.w;
        }
#pragma unroll
        for (int d = 0; d < RVQ_D; ++d) {
            const float qst = r[d] + (cw[d] - r[d]);
            oacc[d] += qst;
            r[d] = r[d] - qst;
        }
    }

    float4* qo = (float4*)(out + (long)p * RVQ_D);
#pragma unroll
    for (int w = 0; w < 8; ++w) {
        float4 v;
        v.x = oacc[w * 4 + 0]; v.y = oacc[w * 4 + 1];
        v.z = oacc[w * 4 + 2]; v.w = oacc[w * 4 + 3];
        qo[w] = v;
    }

    if (p < RVQ_Q) out[LOSS_OFF + p] = 0.0f;
}

// ---------------------------------------------------------------------------
extern "C" void kernel_launch(void* const* d_in, const int* in_sizes, int n_in,
                              void* d_out, int out_size, void* d_ws, size_t ws_size,
                              hipStream_t stream) {
    const float* z  = (const float*)d_in[0];
    const float* cb = (const float*)d_in[1];
    float* out = (float*)d_out;
    float* cbn = (float*)d_ws;  // Q*C floats = 20 KiB

    rvq_cb_norms<<<(RVQ_Q * RVQ_C + 255) / 256, 256, 0, stream>>>(cb, cbn);
    rvq_search<<<NPTS / 4 / 256, 256, 0, stream>>>(z, cb, cbn, out);
    rvq_replay<<<NPTS / 256, 256, 0, stream>>>(z, cb, out);
}